// Round 1
// baseline (469.691 us; speedup 1.0000x reference)
//
#include <hip/hip_runtime.h>
#include <hip/hip_bf16.h>
#include <cstdint>

#define HID 64
#define NHEADS 4
#define NEG_SLOPE 0.2f

// ---------------- CSR build ----------------
__global__ void histo_kernel(const int* __restrict__ dst, int* __restrict__ counts, int E) {
    int i = blockIdx.x * blockDim.x + threadIdx.x;
    if (i < E) atomicAdd(&counts[dst[i]], 1);
}

// single-block chunked exclusive scan over n counters -> offs[n+1], wp[n]
__global__ void scan_kernel(const int* __restrict__ counts, int* __restrict__ offs,
                            int* __restrict__ wp, int n) {
    __shared__ int partial[256];
    const int t = threadIdx.x;
    const int chunk = (n + 255) / 256;
    const int lo = t * chunk;
    const int hi = min(lo + chunk, n);
    int s = 0;
    for (int i = lo; i < hi; ++i) s += counts[i];
    partial[t] = s;
    __syncthreads();
    for (int o = 1; o < 256; o <<= 1) {
        int v = (t >= o) ? partial[t - o] : 0;
        __syncthreads();
        partial[t] += v;
        __syncthreads();
    }
    int run = partial[t] - s;  // exclusive prefix of this thread's chunk
    for (int i = lo; i < hi; ++i) {
        offs[i] = run;
        wp[i] = run;
        run += counts[i];
    }
    if (t == 255) offs[n] = partial[255];
}

__global__ void scatter_kernel(const int* __restrict__ src, const int* __restrict__ dst,
                               int* __restrict__ wp, int* __restrict__ csr, int E) {
    int i = blockIdx.x * blockDim.x + threadIdx.x;
    if (i < E) {
        int d = dst[i];
        int p = atomicAdd(&wp[d], 1);
        csr[p] = src[i];
    }
}

// ---------------- GEMM: H[nrows,OUTC] = X[nrows,K] @ W[K,OUTC] ----------------
// 64x64 output tile per block, 4x4 per thread, K staged in 64-chunks (both LDS
// tiles k-major so compute reads are ds_read_b128).
template <int K, int OUTC>
__global__ __launch_bounds__(256) void gemm_kernel(const float* __restrict__ X,
                                                   const float* __restrict__ W,
                                                   float* __restrict__ H, int nrows) {
    __shared__ float xsT[64][64];  // xsT[k][r] = X[row0+r][k0+k]
    __shared__ float wsT[64][64];  // wsT[k][c] = W[k0+k][c0+c]
    const int tid = threadIdx.x;
    const int tx = tid & 15;        // col group (4 cols)
    const int ty = tid >> 4;        // row group (4 rows)
    const int row0 = blockIdx.x * 64;
    const int c0 = blockIdx.y * 64;

    float acc[4][4];
#pragma unroll
    for (int i = 0; i < 4; ++i)
#pragma unroll
        for (int j = 0; j < 4; ++j) acc[i][j] = 0.f;

    const int xr = tid & 63;         // X stage: row within tile
    const int xkq = (tid >> 6) * 16; // X stage: k-quarter

    for (int k0 = 0; k0 < K; k0 += 64) {
        __syncthreads();
        // stage X transposed: each thread loads 4 float4 along k for one row
#pragma unroll
        for (int j = 0; j < 4; ++j) {
            const int k = xkq + j * 4;
            float4 v = make_float4(0.f, 0.f, 0.f, 0.f);
            const int row = row0 + xr;
            if (row < nrows)
                v = *reinterpret_cast<const float4*>(&X[(size_t)row * K + k0 + k]);
            xsT[k + 0][xr] = v.x;
            xsT[k + 1][xr] = v.y;
            xsT[k + 2][xr] = v.z;
            xsT[k + 3][xr] = v.w;
        }
        // stage W (already k-major): contiguous float4 copies
#pragma unroll
        for (int j = 0; j < 4; ++j) {
            const int fi = tid + j * 256;
            const int k = fi >> 4;
            const int c = (fi & 15) * 4;
            float4 v = *reinterpret_cast<const float4*>(&W[(size_t)(k0 + k) * OUTC + c0 + c]);
            *reinterpret_cast<float4*>(&wsT[k][c]) = v;
        }
        __syncthreads();
#pragma unroll 16
        for (int k = 0; k < 64; ++k) {
            const float4 xv = *reinterpret_cast<const float4*>(&xsT[k][ty * 4]);
            const float4 wv = *reinterpret_cast<const float4*>(&wsT[k][tx * 4]);
            acc[0][0] = fmaf(xv.x, wv.x, acc[0][0]);
            acc[0][1] = fmaf(xv.x, wv.y, acc[0][1]);
            acc[0][2] = fmaf(xv.x, wv.z, acc[0][2]);
            acc[0][3] = fmaf(xv.x, wv.w, acc[0][3]);
            acc[1][0] = fmaf(xv.y, wv.x, acc[1][0]);
            acc[1][1] = fmaf(xv.y, wv.y, acc[1][1]);
            acc[1][2] = fmaf(xv.y, wv.z, acc[1][2]);
            acc[1][3] = fmaf(xv.y, wv.w, acc[1][3]);
            acc[2][0] = fmaf(xv.z, wv.x, acc[2][0]);
            acc[2][1] = fmaf(xv.z, wv.y, acc[2][1]);
            acc[2][2] = fmaf(xv.z, wv.z, acc[2][2]);
            acc[2][3] = fmaf(xv.z, wv.w, acc[2][3]);
            acc[3][0] = fmaf(xv.w, wv.x, acc[3][0]);
            acc[3][1] = fmaf(xv.w, wv.y, acc[3][1]);
            acc[3][2] = fmaf(xv.w, wv.z, acc[3][2]);
            acc[3][3] = fmaf(xv.w, wv.w, acc[3][3]);
        }
    }
#pragma unroll
    for (int r = 0; r < 4; ++r) {
        const int row = row0 + ty * 4 + r;
        if (row < nrows) {
            float4 v = make_float4(acc[r][0], acc[r][1], acc[r][2], acc[r][3]);
            *reinterpret_cast<float4*>(&H[(size_t)row * OUTC + c0 + tx * 4]) = v;
        }
    }
}

// ---------------- per-node attention logits ----------------
// one wave per (node, head): lane = channel; two 64-lane dot products
__global__ void alpha_kernel(const float* __restrict__ h, const float* __restrict__ a_s,
                             const float* __restrict__ a_d, float* __restrict__ alpha_s,
                             float* __restrict__ alpha_d, int n_nodes, int heads) {
    const int gw = (blockIdx.x * blockDim.x + threadIdx.x) >> 6;
    const int lane = threadIdx.x & 63;
    const int total = n_nodes * heads;
    if (gw >= total) return;
    const int n = gw / heads;
    const int hd = gw - n * heads;
    const float v = h[(size_t)n * heads * 64 + hd * 64 + lane];
    float vs = v * a_s[hd * 64 + lane];
    float vd = v * a_d[hd * 64 + lane];
#pragma unroll
    for (int o = 32; o; o >>= 1) {
        vs += __shfl_xor(vs, o);
        vd += __shfl_xor(vd, o);
    }
    if (lane == 0) {
        alpha_s[gw] = vs;
        alpha_d[gw] = vd;
    }
}

// ---------------- aggregation: segment softmax + weighted scatter ----------------
// one block per destination node; one wave per head; lane = channel
template <int HEADS_T, bool RELU>
__global__ void agg_kernel(const float* __restrict__ h, const float* __restrict__ alpha_s,
                           const float* __restrict__ alpha_d, const int* __restrict__ offs,
                           const int* __restrict__ csr, const float* __restrict__ bias,
                           float* __restrict__ out, int n_nodes) {
    const int n = blockIdx.x;
    const int hd = threadIdx.x >> 6;
    const int c = threadIdx.x & 63;
    const int start = offs[n];
    const int end = offs[n + 1];
    const float ad = alpha_d[n * HEADS_T + hd];

    float m = -INFINITY;
    for (int i = start; i < end; ++i) {
        const int s = csr[i];
        float e = alpha_s[s * HEADS_T + hd] + ad;
        e = (e > 0.f) ? e : NEG_SLOPE * e;
        m = fmaxf(m, e);
    }
    float ssum = 0.f, acc = 0.f;
    for (int i = start; i < end; ++i) {
        const int s = csr[i];
        float e = alpha_s[s * HEADS_T + hd] + ad;
        e = (e > 0.f) ? e : NEG_SLOPE * e;
        const float ex = expf(e - m);
        ssum += ex;
        acc = fmaf(ex, h[(size_t)s * (HEADS_T * 64) + hd * 64 + c], acc);
    }
    float o = acc / (ssum + 1e-16f) + bias[hd * 64 + c];
    if (RELU) o = fmaxf(o, 0.f);
    out[(size_t)n * (HEADS_T * 64) + hd * 64 + c] = o;
}

// ---------------- launch ----------------
extern "C" void kernel_launch(void* const* d_in, const int* in_sizes, int n_in,
                              void* d_out, int out_size, void* d_ws, size_t ws_size,
                              hipStream_t stream) {
    const float* x   = (const float*)d_in[0];
    const int*   ei  = (const int*)d_in[1];
    const float* W1  = (const float*)d_in[2];
    const float* a1s = (const float*)d_in[3];
    const float* a1d = (const float*)d_in[4];
    const float* b1  = (const float*)d_in[5];
    const float* W2  = (const float*)d_in[6];
    const float* a2s = (const float*)d_in[7];
    const float* a2d = (const float*)d_in[8];
    const float* b2  = (const float*)d_in[9];
    const float* W3  = (const float*)d_in[10];
    const float* a3s = (const float*)d_in[11];
    const float* a3d = (const float*)d_in[12];
    const float* b3  = (const float*)d_in[13];
    float* out = (float*)d_out;

    const int N = in_sizes[0] / HID;
    const int E = in_sizes[1] / 2;
    const int* src = ei;
    const int* dst = ei + E;

    char* p = (char*)d_ws;
    auto alloc = [&](size_t bytes) {
        char* q = p;
        p += (bytes + 255) & ~(size_t)255;
        return q;
    };
    float* bufA = (float*)alloc((size_t)N * 256 * 4);
    float* bufB = (float*)alloc((size_t)N * 256 * 4);
    float* alpS = (float*)alloc((size_t)N * NHEADS * 4);
    float* alpD = (float*)alloc((size_t)N * NHEADS * 4);
    int* counts = (int*)alloc((size_t)N * 4);
    int* offs   = (int*)alloc((size_t)(N + 1) * 4);
    int* wp     = (int*)alloc((size_t)N * 4);
    int* csr    = (int*)alloc((size_t)E * 4);

    hipMemsetAsync(counts, 0, (size_t)N * 4, stream);
    const int eb = (E + 255) / 256;
    histo_kernel<<<eb, 256, 0, stream>>>(dst, counts, E);
    scan_kernel<<<1, 256, 0, stream>>>(counts, offs, wp, N);
    scatter_kernel<<<eb, 256, 0, stream>>>(src, dst, wp, csr, E);

    const int gb = (N + 63) / 64;

    // layer 1: x[N,64] @ W1[64,256]
    gemm_kernel<64, 256><<<dim3(gb, 4), 256, 0, stream>>>(x, W1, bufA, N);
    alpha_kernel<<<(N * NHEADS * 64) / 256, 256, 0, stream>>>(bufA, a1s, a1d, alpS, alpD, N, NHEADS);
    agg_kernel<NHEADS, true><<<N, NHEADS * 64, 0, stream>>>(bufA, alpS, alpD, offs, csr, b1, bufB, N);

    // layer 2: bufB[N,256] @ W2[256,256]
    gemm_kernel<256, 256><<<dim3(gb, 4), 256, 0, stream>>>(bufB, W2, bufA, N);
    alpha_kernel<<<(N * NHEADS * 64) / 256, 256, 0, stream>>>(bufA, a2s, a2d, alpS, alpD, N, NHEADS);
    agg_kernel<NHEADS, true><<<N, NHEADS * 64, 0, stream>>>(bufA, alpS, alpD, offs, csr, b2, bufB, N);

    // layer 3: bufB[N,256] @ W3[256,64], 1 head, no relu
    gemm_kernel<256, 64><<<dim3(gb, 1), 256, 0, stream>>>(bufB, W3, bufA, N);
    alpha_kernel<<<(N * 1 * 64) / 256, 256, 0, stream>>>(bufA, a3s, a3d, alpS, alpD, N, 1);
    agg_kernel<1, false><<<N, 64, 0, stream>>>(bufA, alpS, alpD, offs, csr, b3, out, N);
}

// Round 2
// 367.076 us; speedup vs baseline: 1.2795x; 1.2795x over previous
//
#include <hip/hip_runtime.h>
#include <hip/hip_bf16.h>
#include <cstdint>

#define HID 64
#define NHEADS 4
#define NEG_SLOPE 0.2f

// ---------------- CSR build ----------------
__global__ void histo_kernel(const int* __restrict__ dst, int* __restrict__ counts, int E) {
    int i = blockIdx.x * blockDim.x + threadIdx.x;
    if (i < E) atomicAdd(&counts[dst[i]], 1);
}

// single-block chunked exclusive scan over n counters -> offs[n+1], wp[n]
__global__ void scan_kernel(const int* __restrict__ counts, int* __restrict__ offs,
                            int* __restrict__ wp, int n) {
    __shared__ int partial[256];
    const int t = threadIdx.x;
    const int chunk = (n + 255) / 256;
    const int lo = t * chunk;
    const int hi = min(lo + chunk, n);
    int s = 0;
    for (int i = lo; i < hi; ++i) s += counts[i];
    partial[t] = s;
    __syncthreads();
    for (int o = 1; o < 256; o <<= 1) {
        int v = (t >= o) ? partial[t - o] : 0;
        __syncthreads();
        partial[t] += v;
        __syncthreads();
    }
    int run = partial[t] - s;  // exclusive prefix of this thread's chunk
    for (int i = lo; i < hi; ++i) {
        offs[i] = run;
        wp[i] = run;
        run += counts[i];
    }
    if (t == 255) offs[n] = partial[255];
}

__global__ void scatter_kernel(const int* __restrict__ src, const int* __restrict__ dst,
                               int* __restrict__ wp, int* __restrict__ csr, int E) {
    int i = blockIdx.x * blockDim.x + threadIdx.x;
    if (i < E) {
        int d = dst[i];
        int p = atomicAdd(&wp[d], 1);
        csr[p] = src[i];
    }
}

// ---------------- GEMM: H[nrows,OUTC] = X[nrows,K] @ W[K,OUTC] ----------------
template <int K, int OUTC>
__global__ __launch_bounds__(256) void gemm_kernel(const float* __restrict__ X,
                                                   const float* __restrict__ W,
                                                   float* __restrict__ H, int nrows) {
    __shared__ float xsT[64][64];  // xsT[k][r] = X[row0+r][k0+k]
    __shared__ float wsT[64][64];  // wsT[k][c] = W[k0+k][c0+c]
    const int tid = threadIdx.x;
    const int tx = tid & 15;        // col group (4 cols)
    const int ty = tid >> 4;        // row group (4 rows)
    const int row0 = blockIdx.x * 64;
    const int c0 = blockIdx.y * 64;

    float acc[4][4];
#pragma unroll
    for (int i = 0; i < 4; ++i)
#pragma unroll
        for (int j = 0; j < 4; ++j) acc[i][j] = 0.f;

    const int xr = tid & 63;         // X stage: row within tile
    const int xkq = (tid >> 6) * 16; // X stage: k-quarter

    for (int k0 = 0; k0 < K; k0 += 64) {
        __syncthreads();
#pragma unroll
        for (int j = 0; j < 4; ++j) {
            const int k = xkq + j * 4;
            float4 v = make_float4(0.f, 0.f, 0.f, 0.f);
            const int row = row0 + xr;
            if (row < nrows)
                v = *reinterpret_cast<const float4*>(&X[(size_t)row * K + k0 + k]);
            xsT[k + 0][xr] = v.x;
            xsT[k + 1][xr] = v.y;
            xsT[k + 2][xr] = v.z;
            xsT[k + 3][xr] = v.w;
        }
#pragma unroll
        for (int j = 0; j < 4; ++j) {
            const int fi = tid + j * 256;
            const int k = fi >> 4;
            const int c = (fi & 15) * 4;
            float4 v = *reinterpret_cast<const float4*>(&W[(size_t)(k0 + k) * OUTC + c0 + c]);
            *reinterpret_cast<float4*>(&wsT[k][c]) = v;
        }
        __syncthreads();
#pragma unroll 16
        for (int k = 0; k < 64; ++k) {
            const float4 xv = *reinterpret_cast<const float4*>(&xsT[k][ty * 4]);
            const float4 wv = *reinterpret_cast<const float4*>(&wsT[k][tx * 4]);
            acc[0][0] = fmaf(xv.x, wv.x, acc[0][0]);
            acc[0][1] = fmaf(xv.x, wv.y, acc[0][1]);
            acc[0][2] = fmaf(xv.x, wv.z, acc[0][2]);
            acc[0][3] = fmaf(xv.x, wv.w, acc[0][3]);
            acc[1][0] = fmaf(xv.y, wv.x, acc[1][0]);
            acc[1][1] = fmaf(xv.y, wv.y, acc[1][1]);
            acc[1][2] = fmaf(xv.y, wv.z, acc[1][2]);
            acc[1][3] = fmaf(xv.y, wv.w, acc[1][3]);
            acc[2][0] = fmaf(xv.z, wv.x, acc[2][0]);
            acc[2][1] = fmaf(xv.z, wv.y, acc[2][1]);
            acc[2][2] = fmaf(xv.z, wv.z, acc[2][2]);
            acc[2][3] = fmaf(xv.z, wv.w, acc[2][3]);
            acc[3][0] = fmaf(xv.w, wv.x, acc[3][0]);
            acc[3][1] = fmaf(xv.w, wv.y, acc[3][1]);
            acc[3][2] = fmaf(xv.w, wv.z, acc[3][2]);
            acc[3][3] = fmaf(xv.w, wv.w, acc[3][3]);
        }
    }
#pragma unroll
    for (int r = 0; r < 4; ++r) {
        const int row = row0 + ty * 4 + r;
        if (row < nrows) {
            float4 v = make_float4(acc[r][0], acc[r][1], acc[r][2], acc[r][3]);
            *reinterpret_cast<float4*>(&H[(size_t)row * OUTC + c0 + tx * 4]) = v;
        }
    }
}

// ---------------- per-node attention logits ----------------
__global__ void alpha_kernel(const float* __restrict__ h, const float* __restrict__ a_s,
                             const float* __restrict__ a_d, float* __restrict__ alpha_s,
                             float* __restrict__ alpha_d, int n_nodes, int heads) {
    const int gw = (blockIdx.x * blockDim.x + threadIdx.x) >> 6;
    const int lane = threadIdx.x & 63;
    const int total = n_nodes * heads;
    if (gw >= total) return;
    const int n = gw / heads;
    const int hd = gw - n * heads;
    const float v = h[(size_t)n * heads * 64 + hd * 64 + lane];
    float vs = v * a_s[hd * 64 + lane];
    float vd = v * a_d[hd * 64 + lane];
#pragma unroll
    for (int o = 32; o; o >>= 1) {
        vs += __shfl_xor(vs, o);
        vd += __shfl_xor(vd, o);
    }
    if (lane == 0) {
        alpha_s[gw] = vs;
        alpha_d[gw] = vd;
    }
}

__device__ __forceinline__ float leaky(float e) {
    return (e > 0.f) ? e : NEG_SLOPE * e;
}

// ---------------- segment softmax -> per-edge weights (CSR order) ----------------
// one wave per node; lanes stride the node's edge list
template <int H>
__global__ __launch_bounds__(256) void maxsumw_kernel(const float* __restrict__ alpha_s,
                                                      const float* __restrict__ alpha_d,
                                                      const int* __restrict__ offs,
                                                      const int* __restrict__ csr,
                                                      float* __restrict__ w, int n_nodes) {
    const int n = (blockIdx.x * blockDim.x + threadIdx.x) >> 6;
    const int lane = threadIdx.x & 63;
    if (n >= n_nodes) return;
    const int start = offs[n];
    const int end = offs[n + 1];

    float ad[H], m[H], sum[H];
#pragma unroll
    for (int h = 0; h < H; ++h) {
        ad[h] = alpha_d[n * H + h];
        m[h] = -INFINITY;
        sum[h] = 0.f;
    }
    // pass 1: max
    for (int i = start + lane; i < end; i += 64) {
        const int s = csr[i];
#pragma unroll
        for (int h = 0; h < H; ++h) m[h] = fmaxf(m[h], leaky(alpha_s[s * H + h] + ad[h]));
    }
#pragma unroll
    for (int o = 32; o; o >>= 1)
#pragma unroll
        for (int h = 0; h < H; ++h) m[h] = fmaxf(m[h], __shfl_xor(m[h], o));
    // pass 2: exp + sum, store raw ex
    for (int i = start + lane; i < end; i += 64) {
        const int s = csr[i];
        float ex[H];
#pragma unroll
        for (int h = 0; h < H; ++h) {
            ex[h] = __expf(leaky(alpha_s[s * H + h] + ad[h]) - m[h]);
            sum[h] += ex[h];
        }
        if (H == 4) {
            float4 v = make_float4(ex[0], ex[1], ex[2], ex[3]);
            *reinterpret_cast<float4*>(&w[(size_t)i * 4]) = v;
        } else {
            w[i] = ex[0];
        }
    }
#pragma unroll
    for (int o = 32; o; o >>= 1)
#pragma unroll
        for (int h = 0; h < H; ++h) sum[h] += __shfl_xor(sum[h], o);
    float recip[H];
#pragma unroll
    for (int h = 0; h < H; ++h) recip[h] = 1.f / (sum[h] + 1e-16f);
    // pass 3: normalize
    for (int i = start + lane; i < end; i += 64) {
        if (H == 4) {
            float4 v = *reinterpret_cast<float4*>(&w[(size_t)i * 4]);
            v.x *= recip[0];
            v.y *= recip[1];
            v.z *= recip[2];
            v.w *= recip[3];
            *reinterpret_cast<float4*>(&w[(size_t)i * 4]) = v;
        } else {
            w[i] *= recip[0];
        }
    }
}

// ---------------- aggregation: weighted gather-sum ----------------
// one wave per (node, head); lane = channel; weights precomputed
template <int H, bool RELU>
__global__ __launch_bounds__(256) void agg2_kernel(const float* __restrict__ h,
                                                   const float* __restrict__ w,
                                                   const int* __restrict__ offs,
                                                   const int* __restrict__ csr,
                                                   const float* __restrict__ bias,
                                                   float* __restrict__ out, int n_nodes) {
    int n, hd;
    if (H == 4) {
        n = blockIdx.x;
        hd = threadIdx.x >> 6;
    } else {
        n = blockIdx.x * 4 + (threadIdx.x >> 6);
        hd = 0;
    }
    const int c = threadIdx.x & 63;
    if (n >= n_nodes) return;
    const int start = offs[n];
    const int end = offs[n + 1];

    float acc0 = 0.f, acc1 = 0.f;
    int i = start;
    for (; i + 1 < end; i += 2) {
        const int s0 = csr[i];
        const int s1 = csr[i + 1];
        const float w0 = w[(size_t)i * H + hd];
        const float w1 = w[(size_t)(i + 1) * H + hd];
        acc0 = fmaf(w0, h[(size_t)s0 * (H * 64) + hd * 64 + c], acc0);
        acc1 = fmaf(w1, h[(size_t)s1 * (H * 64) + hd * 64 + c], acc1);
    }
    if (i < end) {
        const int s0 = csr[i];
        const float w0 = w[(size_t)i * H + hd];
        acc0 = fmaf(w0, h[(size_t)s0 * (H * 64) + hd * 64 + c], acc0);
    }
    float o = acc0 + acc1 + bias[hd * 64 + c];
    if (RELU) o = fmaxf(o, 0.f);
    out[(size_t)n * (H * 64) + hd * 64 + c] = o;
}

// ---------------- launch ----------------
extern "C" void kernel_launch(void* const* d_in, const int* in_sizes, int n_in,
                              void* d_out, int out_size, void* d_ws, size_t ws_size,
                              hipStream_t stream) {
    const float* x   = (const float*)d_in[0];
    const int*   ei  = (const int*)d_in[1];
    const float* W1  = (const float*)d_in[2];
    const float* a1s = (const float*)d_in[3];
    const float* a1d = (const float*)d_in[4];
    const float* b1  = (const float*)d_in[5];
    const float* W2  = (const float*)d_in[6];
    const float* a2s = (const float*)d_in[7];
    const float* a2d = (const float*)d_in[8];
    const float* b2  = (const float*)d_in[9];
    const float* W3  = (const float*)d_in[10];
    const float* a3s = (const float*)d_in[11];
    const float* a3d = (const float*)d_in[12];
    const float* b3  = (const float*)d_in[13];
    float* out = (float*)d_out;

    const int N = in_sizes[0] / HID;
    const int E = in_sizes[1] / 2;
    const int* src = ei;
    const int* dst = ei + E;

    char* p = (char*)d_ws;
    auto alloc = [&](size_t bytes) {
        char* q = p;
        p += (bytes + 255) & ~(size_t)255;
        return q;
    };
    float* bufA = (float*)alloc((size_t)N * 256 * 4);
    float* bufB = (float*)alloc((size_t)N * 256 * 4);
    float* alpS = (float*)alloc((size_t)N * NHEADS * 4);
    float* alpD = (float*)alloc((size_t)N * NHEADS * 4);
    float* wbuf = (float*)alloc((size_t)E * NHEADS * 4);
    int* counts = (int*)alloc((size_t)N * 4);
    int* offs   = (int*)alloc((size_t)(N + 1) * 4);
    int* wp     = (int*)alloc((size_t)N * 4);
    int* csr    = (int*)alloc((size_t)E * 4);

    hipMemsetAsync(counts, 0, (size_t)N * 4, stream);
    const int eb = (E + 255) / 256;
    histo_kernel<<<eb, 256, 0, stream>>>(dst, counts, E);
    scan_kernel<<<1, 256, 0, stream>>>(counts, offs, wp, N);
    scatter_kernel<<<eb, 256, 0, stream>>>(src, dst, wp, csr, E);

    const int gb = (N + 63) / 64;
    const int nwb = (N * 64 + 255) / 256;  // maxsumw: wave per node

    // layer 1: x[N,64] @ W1[64,256]
    gemm_kernel<64, 256><<<dim3(gb, 4), 256, 0, stream>>>(x, W1, bufA, N);
    alpha_kernel<<<(N * NHEADS * 64 + 255) / 256, 256, 0, stream>>>(bufA, a1s, a1d, alpS, alpD, N, NHEADS);
    maxsumw_kernel<NHEADS><<<nwb, 256, 0, stream>>>(alpS, alpD, offs, csr, wbuf, N);
    agg2_kernel<NHEADS, true><<<N, 256, 0, stream>>>(bufA, wbuf, offs, csr, b1, bufB, N);

    // layer 2: bufB[N,256] @ W2[256,256]
    gemm_kernel<256, 256><<<dim3(gb, 4), 256, 0, stream>>>(bufB, W2, bufA, N);
    alpha_kernel<<<(N * NHEADS * 64 + 255) / 256, 256, 0, stream>>>(bufA, a2s, a2d, alpS, alpD, N, NHEADS);
    maxsumw_kernel<NHEADS><<<nwb, 256, 0, stream>>>(alpS, alpD, offs, csr, wbuf, N);
    agg2_kernel<NHEADS, true><<<N, 256, 0, stream>>>(bufA, wbuf, offs, csr, b2, bufB, N);

    // layer 3: bufB[N,256] @ W3[256,64], 1 head, no relu
    gemm_kernel<256, 64><<<dim3(gb, 1), 256, 0, stream>>>(bufB, W3, bufA, N);
    alpha_kernel<<<(N * 1 * 64 + 255) / 256, 256, 0, stream>>>(bufA, a3s, a3d, alpS, alpD, N, 1);
    maxsumw_kernel<1><<<nwb, 256, 0, stream>>>(alpS, alpD, offs, csr, wbuf, N);
    agg2_kernel<1, false><<<(N + 3) / 4, 256, 0, stream>>>(bufA, wbuf, offs, csr, b3, out, N);
}